// Round 4
// baseline (97.928 us; speedup 1.0000x reference)
//
#include <hip/hip_runtime.h>

// Bilinear 2x downsample (scale exactly 2.0, half-pixel centers) == 2x2 avg pool:
//   out[n,c,y,x] = rint(0.25*(in[2y,2x]+in[2y,2x+1]+in[2y+1,2x]+in[2y+1,2x+1]))
// d_out is int32 (harness canonicalizes uint8 -> int32; verified round 2).
// 4 outputs/thread; nontemporal 16B loads/stores via clang ext_vector_type
// (HIP_vector_type structs are rejected by __builtin_nontemporal_*).

#define W_IN   2048
#define H_IN   2048

typedef float  f32x4 __attribute__((ext_vector_type(4)));
typedef int    i32x4 __attribute__((ext_vector_type(4)));

__global__ __launch_bounds__(256) void avgpool2x2_round_kernel(
    const float* __restrict__ in, int* __restrict__ out, int total_quads) {
    int idx = blockIdx.x * blockDim.x + threadIdx.x;
    if (idx >= total_quads) return;

    // idx enumerates (nc, y, xquad): xquad in [0,256), y in [0,1024), nc in [0,24)
    int xq = idx & 255;          // quad of output columns: 4*xq .. 4*xq+3
    int y  = (idx >> 8) & 1023;  // output row
    int nc = idx >> 18;          // fused N*C index

    // Input rows 2y, 2y+1; cols 8*xq .. 8*xq+7 -> two 16B loads per row
    const f32x4* row0 = reinterpret_cast<const f32x4*>(
        in + ((size_t)nc * H_IN + (size_t)(y << 1)) * W_IN) + (xq << 1);
    const f32x4* row1 = row0 + (W_IN / 4);

    f32x4 a0 = __builtin_nontemporal_load(row0);
    f32x4 a1 = __builtin_nontemporal_load(row0 + 1);
    f32x4 b0 = __builtin_nontemporal_load(row1);
    f32x4 b1 = __builtin_nontemporal_load(row1 + 1);

    // round-half-to-even conversion matches jnp.round
    i32x4 o;
    o.x = __float2int_rn((a0.x + a0.y + b0.x + b0.y) * 0.25f);
    o.y = __float2int_rn((a0.z + a0.w + b0.z + b0.w) * 0.25f);
    o.z = __float2int_rn((a1.x + a1.y + b1.x + b1.y) * 0.25f);
    o.w = __float2int_rn((a1.z + a1.w + b1.z + b1.w) * 0.25f);

    __builtin_nontemporal_store(o, reinterpret_cast<i32x4*>(out) + idx);
}

extern "C" void kernel_launch(void* const* d_in, const int* in_sizes, int n_in,
                              void* d_out, int out_size, void* d_ws, size_t ws_size,
                              hipStream_t stream) {
    const float* img = (const float*)d_in[3];
    int* out = (int*)d_out;

    int total_quads = out_size / 4;  // 8*3*1024*256 = 6,291,456
    int block = 256;
    int grid = (total_quads + block - 1) / block;

    avgpool2x2_round_kernel<<<grid, block, 0, stream>>>(img, out, total_quads);
}

// Round 5
// 93.408 us; speedup vs baseline: 1.0484x; 1.0484x over previous
//
#include <hip/hip_runtime.h>

// Bilinear 2x downsample (scale exactly 2.0, half-pixel centers) == 2x2 avg pool:
//   out[n,c,y,x] = rint(0.25*(in[2y,2x]+in[2y,2x+1]+in[2y+1,2x]+in[2y+1,2x+1]))
// d_out is int32 (harness canonicalizes uint8 -> int32; verified round 2).
//
// Layout: one block (256 threads) per output row (1024 px).
// Every load/store instruction is wave-dense:
//   loads : lane t reads f32x4 at row_f4[t] and row_f4[t+256]  (4 KiB dense/instr/block)
//   stores: lane t writes int2 at out2[t] and out2[t+256]       (2 KiB dense/instr/block)
// No nontemporal hints (round 4 showed they regress: 90.4 -> 97.9 us).

#define W_IN   2048
#define H_IN   2048

typedef float f32x4 __attribute__((ext_vector_type(4)));
typedef int   i32x2 __attribute__((ext_vector_type(2)));

__global__ __launch_bounds__(256) void avgpool2x2_round_kernel(
    const float* __restrict__ in, int* __restrict__ out) {
    int b  = blockIdx.x;       // [0, 24*1024): fused (nc, y)
    int y  = b & 1023;         // output row
    int nc = b >> 10;          // fused N*C index
    int t  = threadIdx.x;      // [0, 256)

    // Input rows 2y and 2y+1 of image nc
    const f32x4* row0 = reinterpret_cast<const f32x4*>(
        in + ((size_t)nc * H_IN + (size_t)(y << 1)) * W_IN);
    const f32x4* row1 = row0 + (W_IN / 4);

    f32x4 a0 = row0[t];
    f32x4 a1 = row0[t + 256];
    f32x4 b0 = row1[t];
    f32x4 b1 = row1[t + 256];

    // round-half-to-even conversion matches jnp.round
    i32x2 o0, o1;
    o0.x = __float2int_rn((a0.x + a0.y + b0.x + b0.y) * 0.25f);
    o0.y = __float2int_rn((a0.z + a0.w + b0.z + b0.w) * 0.25f);
    o1.x = __float2int_rn((a1.x + a1.y + b1.x + b1.y) * 0.25f);
    o1.y = __float2int_rn((a1.z + a1.w + b1.z + b1.w) * 0.25f);

    i32x2* orow = reinterpret_cast<i32x2*>(out + ((size_t)nc * 1024 + y) * 1024);
    orow[t]       = o0;
    orow[t + 256] = o1;
}

extern "C" void kernel_launch(void* const* d_in, const int* in_sizes, int n_in,
                              void* d_out, int out_size, void* d_ws, size_t ws_size,
                              hipStream_t stream) {
    const float* img = (const float*)d_in[3];
    int* out = (int*)d_out;

    int grid = 24 * 1024;  // one block per output row (8*3 images x 1024 rows)
    avgpool2x2_round_kernel<<<grid, 256, 0, stream>>>(img, out);
}